// Round 10
// baseline (115.505 us; speedup 1.0000x reference)
//
#include <hip/hip_runtime.h>

// Rel-pos attention, re-tiled MFMA design, r10: K2 widened to 1024 threads
// (16 waves) at unchanged 74 KB LDS -> 2 blocks/CU = 32 waves/CU (8/SIMD,
// HW max; was 16). __launch_bounds__(1024,8) caps VGPR at 64 (audited fit).
// K1/K3 byte-identical to r9. B=4, H=8, S=512, D=64.
//
// K1 qk_mfma : SK[b,h,s,t] = Q.K^T -> bf16 in d_ws (or fp32 in pout fallback).
// K2 attn_v9 : one block per (b,s), 1024 thr. Stage R[b,s] -> LDS bf16 ONCE.
//              rel = Q.R^T (MFMA, 2 tiles/wave) -> Sb; softmax (8 waves);
//              ans2 = P.R (MFMA, 8 waves + partial combine) -> ans.
// K3 pv_mfma : one block per (b,h,s-tile32), 512 thr. Stage V[b,h] -> LDS;
//              ans += P.V (MFMA), P streamed from pout.

typedef __attribute__((ext_vector_type(8))) short short8;
typedef __attribute__((ext_vector_type(4))) float f32x4;

#define MFMA16(a, b, c) __builtin_amdgcn_mfma_f32_16x16x32_bf16(a, b, c, 0, 0, 0)

__device__ __forceinline__ unsigned short f2bf(float x) {
  unsigned int u = __float_as_uint(x);
  u += 0x7fffu + ((u >> 16) & 1u);   // RNE
  return (unsigned short)(u >> 16);
}
__device__ __forceinline__ float bf2f(unsigned int s) {
  return __uint_as_float(s << 16);
}
__device__ __forceinline__ short8 pack8(const float4& a, const float4& b) {
  short8 r;
  r[0] = (short)f2bf(a.x); r[1] = (short)f2bf(a.y);
  r[2] = (short)f2bf(a.z); r[3] = (short)f2bf(a.w);
  r[4] = (short)f2bf(b.x); r[5] = (short)f2bf(b.y);
  r[6] = (short)f2bf(b.z); r[7] = (short)f2bf(b.w);
  return r;
}
__device__ __forceinline__ int RLI(int t, int d) {
  return ((t << 6) | d) ^ ((((t & 7) ^ ((t >> 3) & 7))) << 3);
}
__device__ __forceinline__ int SBI(int h, int t) {
  return ((h << 9) | t) ^ ((h & 7) << 3);
}

// ---------------- K1: SK = Q.K^T per (b,h), 64x64 tiles (proven) ----------
template <bool WSK>
__global__ __launch_bounds__(256, 4)
void qk_mfma(const float* __restrict__ Q, const float* __restrict__ K,
             void* __restrict__ skout) {
  const int bh   = blockIdx.x >> 6;
  const int tile = blockIdx.x & 63;
  const int s0 = (tile >> 3) << 6;
  const int t0 = (tile & 7) << 6;
  const int w    = threadIdx.x >> 6;
  const int lane = threadIdx.x & 63;
  const int rrow = lane & 15;
  const int kg   = lane >> 4;

  const float* Qb = Q + ((size_t)bh << 15);
  const float* Kb = K + ((size_t)bh << 15);

  const float* qp = Qb + (((s0 + (w << 4) + rrow) << 6) + (kg << 3));
  const short8 a0 = pack8(*reinterpret_cast<const float4*>(qp),
                          *reinterpret_cast<const float4*>(qp + 4));
  const short8 a1 = pack8(*reinterpret_cast<const float4*>(qp + 32),
                          *reinterpret_cast<const float4*>(qp + 36));

  float4 b0, b1, b2, b3;
  {
    const float* kp = Kb + (((t0 + rrow) << 6) + (kg << 3));
    b0 = *reinterpret_cast<const float4*>(kp);
    b1 = *reinterpret_cast<const float4*>(kp + 4);
    b2 = *reinterpret_cast<const float4*>(kp + 32);
    b3 = *reinterpret_cast<const float4*>(kp + 36);
  }
#pragma unroll
  for (int nt = 0; nt < 4; ++nt) {
    const short8 bb0 = pack8(b0, b1);
    const short8 bb1 = pack8(b2, b3);
    if (nt < 3) {
      const float* kp = Kb + (((t0 + ((nt + 1) << 4) + rrow) << 6) + (kg << 3));
      b0 = *reinterpret_cast<const float4*>(kp);
      b1 = *reinterpret_cast<const float4*>(kp + 4);
      b2 = *reinterpret_cast<const float4*>(kp + 32);
      b3 = *reinterpret_cast<const float4*>(kp + 36);
    }
    f32x4 c = {0.0f, 0.0f, 0.0f, 0.0f};
    c = MFMA16(a0, bb0, c);
    c = MFMA16(a1, bb1, c);
    const int tcol = t0 + (nt << 4) + rrow;
    const int srow = s0 + (w << 4) + (kg << 2);
    if constexpr (WSK) {
      unsigned short* ob = (unsigned short*)skout + ((size_t)bh << 18);
#pragma unroll
      for (int r = 0; r < 4; ++r)
        ob[(size_t)(srow + r) * 512 + tcol] = f2bf(c[r]);
    } else {
      float* ob = (float*)skout + ((size_t)bh << 18);
#pragma unroll
      for (int r = 0; r < 4; ++r)
        ob[(size_t)(srow + r) * 512 + tcol] = c[r];
    }
  }
}

// ---------------- K2: per (b,s): rel + softmax + ans2, 1024 threads -------
template <bool WSK>
__global__ __launch_bounds__(1024, 8)
void attn_v9(const float* __restrict__ Q, const float* __restrict__ R,
             const int* __restrict__ Mk, float* __restrict__ ans,
             float* __restrict__ pout, const void* __restrict__ skin) {
  __shared__ __align__(16) unsigned short smem[8 * 512 + 512 * 64];  // 72 KB
  __shared__ __align__(16) float Pp[4][8][16];                        // 2 KB
  unsigned short* Sb = smem;
  unsigned short* Rl = smem + 8 * 512;

  const int tid = threadIdx.x;
  const int b = blockIdx.x >> 9;
  const int s = blockIdx.x & 511;
  const int bh0 = b << 3;

  const float* Rg = R + ((size_t)((b << 9) + s) << 15);

  // ---- stage R[b,s] 512x64 fp32 -> Rl bf16 (swizzled), 8 float4/thread ----
  {
    const int d4 = tid & 15;     // float4 col
    const int tr = tid >> 4;     // 0..63: row within 64-row stripe
#pragma unroll
    for (int pg = 0; pg < 2; ++pg) {
      float4 tmp[4];
#pragma unroll
      for (int j = 0; j < 4; ++j) {
        const int t = (pg << 8) + (j << 6) + tr;
        tmp[j] = *reinterpret_cast<const float4*>(Rg + (t << 6) + (d4 << 2));
      }
#pragma unroll
      for (int j = 0; j < 4; ++j) {
        const int t = (pg << 8) + (j << 6) + tr;
        unsigned short* dst = &Rl[RLI(t, d4 << 2)];
        dst[0] = f2bf(tmp[j].x); dst[1] = f2bf(tmp[j].y);
        dst[2] = f2bf(tmp[j].z); dst[3] = f2bf(tmp[j].w);
      }
    }
  }
  __syncthreads();

  const int lane = tid & 63;
  const int w    = tid >> 6;   // 0..15
  const int nn   = lane & 15;
  const int kg   = lane >> 4;

  // ---- rel[h,t] = Q[h,:].R[t,:] (A=Q padded to 16 rows, B=R) -> Sb ----
  // 16 waves x 2 t-tiles each.
  {
    const int hq = nn & 7;
    const float* Qg = Q + ((size_t)(((bh0 + hq) << 9) + s) << 6);
    const short8 aq0 = pack8(*reinterpret_cast<const float4*>(Qg + (kg << 3)),
                             *reinterpret_cast<const float4*>(Qg + (kg << 3) + 4));
    const short8 aq1 = pack8(*reinterpret_cast<const float4*>(Qg + 32 + (kg << 3)),
                             *reinterpret_cast<const float4*>(Qg + 36 + (kg << 3)));

#pragma unroll
    for (int i = 0; i < 2; ++i) {
      const int t0 = ((w << 1) + i) << 4;
      const short8 bb0 = *reinterpret_cast<const short8*>(&Rl[RLI(t0 + nn, kg << 3)]);
      const short8 bb1 = *reinterpret_cast<const short8*>(&Rl[RLI(t0 + nn, 32 + (kg << 3))]);
      f32x4 c = {0.0f, 0.0f, 0.0f, 0.0f};
      c = MFMA16(aq0, bb0, c);
      c = MFMA16(aq1, bb1, c);
      if (kg < 2) {
#pragma unroll
        for (int r = 0; r < 4; ++r)
          Sb[SBI((kg << 2) + r, t0 + nn)] = f2bf(c[r]);
      }
    }
  }
  __syncthreads();

  // ---- softmax row h = w (waves 0..7; waves 8..15 idle to barrier) ----
  if (w < 8) {
    const int h = w;
    float bias[8];
#pragma unroll
    for (int k = 0; k < 8; ++k)
      bias[k] = Mk[(b << 9) + lane + (k << 6)] ? 0.0f : -1.0e9f;

    float* po = pout + ((size_t)(bh0 + h) << 18) + ((size_t)s << 9);
    const unsigned short* skw =
        WSK ? (const unsigned short*)skin + ((size_t)(bh0 + h) << 18) + ((size_t)s << 9)
            : nullptr;
    const float* skf =
        WSK ? nullptr
            : (const float*)skin + ((size_t)(bh0 + h) << 18) + ((size_t)s << 9);

    float v[8];
#pragma unroll
    for (int k = 0; k < 8; ++k) {
      const int t = lane + (k << 6);
      const float skv = WSK ? bf2f((unsigned int)skw[t]) : skf[t];
      v[k] = (bf2f((unsigned int)Sb[SBI(h, t)]) + skv) * 0.125f + bias[k];
    }
    float m = v[0];
#pragma unroll
    for (int k = 1; k < 8; ++k) m = fmaxf(m, v[k]);
    m = fmaxf(m, __shfl_xor(m, 1));
    m = fmaxf(m, __shfl_xor(m, 2));
    m = fmaxf(m, __shfl_xor(m, 4));
    m = fmaxf(m, __shfl_xor(m, 8));
    m = fmaxf(m, __shfl_xor(m, 16));
    m = fmaxf(m, __shfl_xor(m, 32));

    float e[8], ss = 0.0f;
#pragma unroll
    for (int k = 0; k < 8; ++k) { e[k] = __expf(v[k] - m); ss += e[k]; }
    ss += __shfl_xor(ss, 1);
    ss += __shfl_xor(ss, 2);
    ss += __shfl_xor(ss, 4);
    ss += __shfl_xor(ss, 8);
    ss += __shfl_xor(ss, 16);
    ss += __shfl_xor(ss, 32);
    const float inv = 1.0f / ss;

#pragma unroll
    for (int k = 0; k < 8; ++k) {
      const float p = e[k] * inv;
      const int t = lane + (k << 6);
      po[t] = p;
      Sb[SBI(h, t)] = f2bf(p);
    }
  }
  __syncthreads();

  // ---- ans2[h,d] = sum_t P[h,t].R[t,d]; waves 0..7 = (d-tile, k-half) ----
  {
    const int dt = w & 3;        // d-tile: cols dt*16..dt*16+15
    const int kh = (w >> 2) & 1; // k-half: ks 8*kh..8*kh+7
    const int n0 = dt << 4;

    f32x4 acc = {0.0f, 0.0f, 0.0f, 0.0f};
    if (w < 8) {
#pragma unroll
      for (int k8 = 0; k8 < 8; ++k8) {
        const int tb = (((kh << 3) + k8) << 5) + (kg << 3);
        const short8 af = *reinterpret_cast<const short8*>(&Sb[SBI(nn, tb)]);
        short8 bf;
#pragma unroll
        for (int j = 0; j < 8; ++j)
          bf[j] = (short)Rl[RLI(tb + j, n0 + nn)];
        acc = MFMA16(af, bf, acc);
      }
      if (kh == 1 && kg < 2) {
#pragma unroll
        for (int r = 0; r < 4; ++r)
          Pp[dt][(kg << 2) + r][nn] = acc[r];
      }
    }
    __syncthreads();
    if (w < 8 && kh == 0 && kg < 2) {
#pragma unroll
      for (int r = 0; r < 4; ++r) {
        const int h = (kg << 2) + r;
        ans[((size_t)(((bh0 + h) << 9) + s) << 6) + n0 + nn] =
            acc[r] + Pp[dt][h][nn];
      }
    }
  }
}

// ---------------- K3: ans += P.V per (b,h,32-row s-tile), 512 threads -----
__global__ __launch_bounds__(512, 4)
void pv_mfma(const float* __restrict__ V, const float* __restrict__ pout,
             float* __restrict__ ans) {
  __shared__ __align__(16) unsigned short Vl[512 * 64];   // 64 KB

  const int tid = threadIdx.x;
  const int bh = blockIdx.x >> 4;
  const int s0 = (blockIdx.x & 15) << 5;

  const float* Vg = V + ((size_t)bh << 15);
  {
    const int d4 = tid & 15;
    const int tr = tid >> 4;     // 0..31
#pragma unroll
    for (int pg = 0; pg < 2; ++pg) {
      float4 tmp[8];
#pragma unroll
      for (int j = 0; j < 8; ++j) {
        const int t = (pg << 8) + (j << 5) + tr;
        tmp[j] = *reinterpret_cast<const float4*>(Vg + (t << 6) + (d4 << 2));
      }
#pragma unroll
      for (int j = 0; j < 8; ++j) {
        const int t = (pg << 8) + (j << 5) + tr;
        unsigned short* dst = &Vl[RLI(t, d4 << 2)];
        dst[0] = f2bf(tmp[j].x); dst[1] = f2bf(tmp[j].y);
        dst[2] = f2bf(tmp[j].z); dst[3] = f2bf(tmp[j].w);
      }
    }
  }
  __syncthreads();

  const int lane = tid & 63;
  const int w    = tid >> 6;     // 0..7
  const int nn   = lane & 15;
  const int kg   = lane >> 4;
  const int rw   = w & 1;        // s-subtile (16 rows)
  const int cq   = w >> 1;       // d-tile: cols cq*16..cq*16+15
  const int n0   = cq << 4;
  const int srow = s0 + (rw << 4) + nn;

  const float* Pg = pout + ((size_t)bh << 18) + ((size_t)srow << 9);

  f32x4 acc = {0.f, 0.f, 0.f, 0.f};

  float4 pa = *reinterpret_cast<const float4*>(Pg + (kg << 3));
  float4 pb = *reinterpret_cast<const float4*>(Pg + (kg << 3) + 4);
#pragma unroll
  for (int ks = 0; ks < 16; ++ks) {
    const short8 af = pack8(pa, pb);
    if (ks < 15) {
      pa = *reinterpret_cast<const float4*>(Pg + ((ks + 1) << 5) + (kg << 3));
      pb = *reinterpret_cast<const float4*>(Pg + ((ks + 1) << 5) + (kg << 3) + 4);
    }
    const int tb = (ks << 5) + (kg << 3);
    short8 bf;
#pragma unroll
    for (int j = 0; j < 8; ++j)
      bf[j] = (short)Vl[RLI(tb + j, n0 + nn)];
    acc = MFMA16(af, bf, acc);
  }

  {
    const int sb = s0 + (rw << 4) + (kg << 2);
#pragma unroll
    for (int r = 0; r < 4; ++r) {
      float* ap = ans + ((size_t)bh << 15) + ((size_t)(sb + r) << 6) + n0 + nn;
      ap[0] += acc[r];
    }
  }
}

extern "C" void kernel_launch(void* const* d_in, const int* in_sizes, int n_in,
                              void* d_out, int out_size, void* d_ws, size_t ws_size,
                              hipStream_t stream) {
  const float* Q  = (const float*)d_in[0];
  const float* K  = (const float*)d_in[1];
  const float* V  = (const float*)d_in[2];
  const float* R  = (const float*)d_in[3];
  const int*   Mk = (const int*)d_in[4];
  float* ans  = (float*)d_out;
  float* pout = ans + (size_t)4 * 8 * 512 * 64;  // p_attn region
  (void)in_sizes; (void)n_in; (void)out_size;

  const size_t sk_bf16_bytes = (size_t)4 * 8 * 512 * 512 * 2;  // 16.8 MB

  if (ws_size >= sk_bf16_bytes) {
    hipLaunchKernelGGL((qk_mfma<true>), dim3(2048), dim3(256), 0, stream,
                       Q, K, d_ws);
    hipLaunchKernelGGL((attn_v9<true>), dim3(2048), dim3(1024), 0, stream,
                       Q, R, Mk, ans, pout, d_ws);
  } else {
    hipLaunchKernelGGL((qk_mfma<false>), dim3(2048), dim3(256), 0, stream,
                       Q, K, pout);
    hipLaunchKernelGGL((attn_v9<false>), dim3(2048), dim3(1024), 0, stream,
                       Q, R, Mk, ans, pout, pout);
  }
  hipLaunchKernelGGL(pv_mfma, dim3(512), dim3(512), 0, stream, V, pout, ans);
}

// Round 11
// 106.073 us; speedup vs baseline: 1.0889x; 1.0889x over previous
//
#include <hip/hip_runtime.h>

// Rel-pos attention, r11: (a) SK stored bf16 IN-PLACE in pout rows (first
// 1KB of each 2KB p-row; owning wave reads before overwriting with fp32 p)
// -> kills 34MB of SK round-trip without d_ws. (b) K2 double-buffers R
// staging (half-1 in regs while rel(half-0) computes). K3 unchanged.
// B=4, H=8, S=512, D=64.

typedef __attribute__((ext_vector_type(8))) short short8;
typedef __attribute__((ext_vector_type(4))) float f32x4;

#define MFMA16(a, b, c) __builtin_amdgcn_mfma_f32_16x16x32_bf16(a, b, c, 0, 0, 0)

__device__ __forceinline__ unsigned short f2bf(float x) {
  unsigned int u = __float_as_uint(x);
  u += 0x7fffu + ((u >> 16) & 1u);   // RNE
  return (unsigned short)(u >> 16);
}
__device__ __forceinline__ float bf2f(unsigned int s) {
  return __uint_as_float(s << 16);
}
__device__ __forceinline__ short8 pack8(const float4& a, const float4& b) {
  short8 r;
  r[0] = (short)f2bf(a.x); r[1] = (short)f2bf(a.y);
  r[2] = (short)f2bf(a.z); r[3] = (short)f2bf(a.w);
  r[4] = (short)f2bf(b.x); r[5] = (short)f2bf(b.y);
  r[6] = (short)f2bf(b.z); r[7] = (short)f2bf(b.w);
  return r;
}
__device__ __forceinline__ int RLI(int t, int d) {
  return ((t << 6) | d) ^ ((((t & 7) ^ ((t >> 3) & 7))) << 3);
}
__device__ __forceinline__ int SBI(int h, int t) {
  return ((h << 9) | t) ^ ((h & 7) << 3);
}

// ---------------- K1: SK = Q.K^T per (b,h), bf16 packed into pout rows ----
__global__ __launch_bounds__(256, 4)
void qk_mfma(const float* __restrict__ Q, const float* __restrict__ K,
             float* __restrict__ pout) {
  const int bh   = blockIdx.x >> 6;
  const int tile = blockIdx.x & 63;
  const int s0 = (tile >> 3) << 6;
  const int t0 = (tile & 7) << 6;
  const int w    = threadIdx.x >> 6;
  const int lane = threadIdx.x & 63;
  const int rrow = lane & 15;
  const int kg   = lane >> 4;

  const float* Qb = Q + ((size_t)bh << 15);
  const float* Kb = K + ((size_t)bh << 15);

  const float* qp = Qb + (((s0 + (w << 4) + rrow) << 6) + (kg << 3));
  const short8 a0 = pack8(*reinterpret_cast<const float4*>(qp),
                          *reinterpret_cast<const float4*>(qp + 4));
  const short8 a1 = pack8(*reinterpret_cast<const float4*>(qp + 32),
                          *reinterpret_cast<const float4*>(qp + 36));

  float* pb = pout + ((size_t)bh << 18);

  float4 b0, b1, b2, b3;
  {
    const float* kp = Kb + (((t0 + rrow) << 6) + (kg << 3));
    b0 = *reinterpret_cast<const float4*>(kp);
    b1 = *reinterpret_cast<const float4*>(kp + 4);
    b2 = *reinterpret_cast<const float4*>(kp + 32);
    b3 = *reinterpret_cast<const float4*>(kp + 36);
  }
#pragma unroll
  for (int nt = 0; nt < 4; ++nt) {
    const short8 bb0 = pack8(b0, b1);
    const short8 bb1 = pack8(b2, b3);
    if (nt < 3) {
      const float* kp = Kb + (((t0 + ((nt + 1) << 4) + rrow) << 6) + (kg << 3));
      b0 = *reinterpret_cast<const float4*>(kp);
      b1 = *reinterpret_cast<const float4*>(kp + 4);
      b2 = *reinterpret_cast<const float4*>(kp + 32);
      b3 = *reinterpret_cast<const float4*>(kp + 36);
    }
    f32x4 c = {0.0f, 0.0f, 0.0f, 0.0f};
    c = MFMA16(a0, bb0, c);
    c = MFMA16(a1, bb1, c);
    const int tcol = t0 + (nt << 4) + rrow;
    const int srow = s0 + (w << 4) + (kg << 2);
#pragma unroll
    for (int r = 0; r < 4; ++r) {
      unsigned short* ob =
          reinterpret_cast<unsigned short*>(pb + ((size_t)(srow + r) << 9));
      ob[tcol] = f2bf(c[r]);
    }
  }
}

// ---------------- K2: per (b,s): rel + softmax + ans2, dbuf staging -------
__global__ __launch_bounds__(512, 4)
void attn_v10(const float* __restrict__ Q, const float* __restrict__ R,
              const int* __restrict__ Mk, float* __restrict__ ans,
              float* __restrict__ pout) {
  __shared__ __align__(16) unsigned short smem[8 * 512 + 512 * 64];  // 72 KB
  __shared__ __align__(16) float Pp[4][8][16];                        // 2 KB
  unsigned short* Sb = smem;
  unsigned short* Rl = smem + 8 * 512;

  const int tid = threadIdx.x;
  const int b = blockIdx.x >> 9;
  const int s = blockIdx.x & 511;
  const int bh0 = b << 3;

  const float* Rg = R + ((size_t)((b << 9) + s) << 15);

  const int d4 = tid & 15;     // float4 col
  const int tr = tid >> 4;     // 0..31

  float4 buf[8];
  // ---- load + write half 0 (t 0..255) ----
#pragma unroll
  for (int j = 0; j < 8; ++j)
    buf[j] = *reinterpret_cast<const float4*>(
        Rg + (((j << 5) + tr) << 6) + (d4 << 2));
#pragma unroll
  for (int j = 0; j < 8; ++j) {
    const int t = (j << 5) + tr;
    unsigned short* dst = &Rl[RLI(t, d4 << 2)];
    dst[0] = f2bf(buf[j].x); dst[1] = f2bf(buf[j].y);
    dst[2] = f2bf(buf[j].z); dst[3] = f2bf(buf[j].w);
  }
  // ---- issue half-1 loads (consumed after rel(0)) ----
#pragma unroll
  for (int j = 0; j < 8; ++j)
    buf[j] = *reinterpret_cast<const float4*>(
        Rg + ((256 + (j << 5) + tr) << 6) + (d4 << 2));
  __syncthreads();

  const int lane = tid & 63;
  const int w    = tid >> 6;   // 0..7
  const int nn   = lane & 15;
  const int kg   = lane >> 4;

  // ---- hoist SK (bf16 in pout row) + mask loads; consumed in softmax ----
  float* po = pout + ((size_t)(bh0 + w) << 18) + ((size_t)s << 9);
  const unsigned short* skw = reinterpret_cast<const unsigned short*>(po);
  unsigned int skv[8];
  int mkv[8];
#pragma unroll
  for (int k = 0; k < 8; ++k) {
    skv[k] = skw[lane + (k << 6)];
    mkv[k] = Mk[(b << 9) + lane + (k << 6)];
  }

  // ---- rel A-frags (Q) ----
  const int hq = nn & 7;
  const float* Qg = Q + ((size_t)(((bh0 + hq) << 9) + s) << 6);
  const short8 aq0 = pack8(*reinterpret_cast<const float4*>(Qg + (kg << 3)),
                           *reinterpret_cast<const float4*>(Qg + (kg << 3) + 4));
  const short8 aq1 = pack8(*reinterpret_cast<const float4*>(Qg + 32 + (kg << 3)),
                           *reinterpret_cast<const float4*>(Qg + 36 + (kg << 3)));

  // ---- rel(half 0): waves cover t-tiles 0..15 ----
#pragma unroll
  for (int i = 0; i < 2; ++i) {
    const int t0 = ((w << 1) + i) << 4;
    const short8 bb0 = *reinterpret_cast<const short8*>(&Rl[RLI(t0 + nn, kg << 3)]);
    const short8 bb1 = *reinterpret_cast<const short8*>(&Rl[RLI(t0 + nn, 32 + (kg << 3))]);
    f32x4 c = {0.0f, 0.0f, 0.0f, 0.0f};
    c = MFMA16(aq0, bb0, c);
    c = MFMA16(aq1, bb1, c);
    if (kg < 2) {
#pragma unroll
      for (int r = 0; r < 4; ++r)
        Sb[SBI((kg << 2) + r, t0 + nn)] = f2bf(c[r]);
    }
  }

  // ---- write half 1 to LDS (region disjoint from half-0 reads) ----
#pragma unroll
  for (int j = 0; j < 8; ++j) {
    const int t = 256 + (j << 5) + tr;
    unsigned short* dst = &Rl[RLI(t, d4 << 2)];
    dst[0] = f2bf(buf[j].x); dst[1] = f2bf(buf[j].y);
    dst[2] = f2bf(buf[j].z); dst[3] = f2bf(buf[j].w);
  }
  __syncthreads();

  // ---- rel(half 1) ----
#pragma unroll
  for (int i = 0; i < 2; ++i) {
    const int t0 = 256 + (((w << 1) + i) << 4);
    const short8 bb0 = *reinterpret_cast<const short8*>(&Rl[RLI(t0 + nn, kg << 3)]);
    const short8 bb1 = *reinterpret_cast<const short8*>(&Rl[RLI(t0 + nn, 32 + (kg << 3))]);
    f32x4 c = {0.0f, 0.0f, 0.0f, 0.0f};
    c = MFMA16(aq0, bb0, c);
    c = MFMA16(aq1, bb1, c);
    if (kg < 2) {
#pragma unroll
      for (int r = 0; r < 4; ++r)
        Sb[SBI((kg << 2) + r, t0 + nn)] = f2bf(c[r]);
    }
  }
  __syncthreads();

  // ---- softmax row h = w: (rel + SK)/8 + mask -> p (fp32 over own row) ----
  {
    const int h = w;
    float v[8];
#pragma unroll
    for (int k = 0; k < 8; ++k) {
      const int t = lane + (k << 6);
      v[k] = (bf2f((unsigned int)Sb[SBI(h, t)]) + bf2f(skv[k])) * 0.125f +
             (mkv[k] ? 0.0f : -1.0e9f);
    }
    float m = v[0];
#pragma unroll
    for (int k = 1; k < 8; ++k) m = fmaxf(m, v[k]);
    m = fmaxf(m, __shfl_xor(m, 1));
    m = fmaxf(m, __shfl_xor(m, 2));
    m = fmaxf(m, __shfl_xor(m, 4));
    m = fmaxf(m, __shfl_xor(m, 8));
    m = fmaxf(m, __shfl_xor(m, 16));
    m = fmaxf(m, __shfl_xor(m, 32));

    float e[8], ss = 0.0f;
#pragma unroll
    for (int k = 0; k < 8; ++k) { e[k] = __expf(v[k] - m); ss += e[k]; }
    ss += __shfl_xor(ss, 1);
    ss += __shfl_xor(ss, 2);
    ss += __shfl_xor(ss, 4);
    ss += __shfl_xor(ss, 8);
    ss += __shfl_xor(ss, 16);
    ss += __shfl_xor(ss, 32);
    const float inv = 1.0f / ss;

#pragma unroll
    for (int k = 0; k < 8; ++k) {
      const float p = e[k] * inv;
      const int t = lane + (k << 6);
      po[t] = p;
      Sb[SBI(h, t)] = f2bf(p);
    }
  }
  __syncthreads();

  // ---- ans2[h,d] = sum_t P[h,t].R[t,d]; 8 waves = (d-tile, k-half) ----
  {
    const int dt = w & 3;
    const int kh = (w >> 2) & 1;
    const int n0 = dt << 4;

    f32x4 acc = {0.0f, 0.0f, 0.0f, 0.0f};
#pragma unroll
    for (int k8 = 0; k8 < 8; ++k8) {
      const int tb = (((kh << 3) + k8) << 5) + (kg << 3);
      const short8 af = *reinterpret_cast<const short8*>(&Sb[SBI(nn, tb)]);
      short8 bf;
#pragma unroll
      for (int j = 0; j < 8; ++j)
        bf[j] = (short)Rl[RLI(tb + j, n0 + nn)];
      acc = MFMA16(af, bf, acc);
    }
    if (kh == 1 && kg < 2) {
#pragma unroll
      for (int r = 0; r < 4; ++r)
        Pp[dt][(kg << 2) + r][nn] = acc[r];
    }
    __syncthreads();
    if (kh == 0 && kg < 2) {
#pragma unroll
      for (int r = 0; r < 4; ++r) {
        const int h = (kg << 2) + r;
        ans[((size_t)(((bh0 + h) << 9) + s) << 6) + n0 + nn] =
            acc[r] + Pp[dt][h][nn];
      }
    }
  }
}

// ---------------- K3: ans += P.V per (b,h,32-row s-tile), 512 threads -----
__global__ __launch_bounds__(512, 4)
void pv_mfma(const float* __restrict__ V, const float* __restrict__ pout,
             float* __restrict__ ans) {
  __shared__ __align__(16) unsigned short Vl[512 * 64];   // 64 KB

  const int tid = threadIdx.x;
  const int bh = blockIdx.x >> 4;
  const int s0 = (blockIdx.x & 15) << 5;

  const float* Vg = V + ((size_t)bh << 15);
  {
    const int d4 = tid & 15;
    const int tr = tid >> 4;     // 0..31
#pragma unroll
    for (int pg = 0; pg < 2; ++pg) {
      float4 tmp[8];
#pragma unroll
      for (int j = 0; j < 8; ++j) {
        const int t = (pg << 8) + (j << 5) + tr;
        tmp[j] = *reinterpret_cast<const float4*>(Vg + (t << 6) + (d4 << 2));
      }
#pragma unroll
      for (int j = 0; j < 8; ++j) {
        const int t = (pg << 8) + (j << 5) + tr;
        unsigned short* dst = &Vl[RLI(t, d4 << 2)];
        dst[0] = f2bf(tmp[j].x); dst[1] = f2bf(tmp[j].y);
        dst[2] = f2bf(tmp[j].z); dst[3] = f2bf(tmp[j].w);
      }
    }
  }
  __syncthreads();

  const int lane = tid & 63;
  const int w    = tid >> 6;     // 0..7
  const int nn   = lane & 15;
  const int kg   = lane >> 4;
  const int rw   = w & 1;
  const int cq   = w >> 1;
  const int n0   = cq << 4;
  const int srow = s0 + (rw << 4) + nn;

  const float* Pg = pout + ((size_t)bh << 18) + ((size_t)srow << 9);

  f32x4 acc = {0.f, 0.f, 0.f, 0.f};

  float4 pa = *reinterpret_cast<const float4*>(Pg + (kg << 3));
  float4 pb = *reinterpret_cast<const float4*>(Pg + (kg << 3) + 4);
#pragma unroll
  for (int ks = 0; ks < 16; ++ks) {
    const short8 af = pack8(pa, pb);
    if (ks < 15) {
      pa = *reinterpret_cast<const float4*>(Pg + ((ks + 1) << 5) + (kg << 3));
      pb = *reinterpret_cast<const float4*>(Pg + ((ks + 1) << 5) + (kg << 3) + 4);
    }
    const int tb = (ks << 5) + (kg << 3);
    short8 bf;
#pragma unroll
    for (int j = 0; j < 8; ++j)
      bf[j] = (short)Vl[RLI(tb + j, n0 + nn)];
    acc = MFMA16(af, bf, acc);
  }

  {
    const int sb = s0 + (rw << 4) + (kg << 2);
#pragma unroll
    for (int r = 0; r < 4; ++r) {
      float* ap = ans + ((size_t)bh << 15) + ((size_t)(sb + r) << 6) + n0 + nn;
      ap[0] += acc[r];
    }
  }
}

extern "C" void kernel_launch(void* const* d_in, const int* in_sizes, int n_in,
                              void* d_out, int out_size, void* d_ws, size_t ws_size,
                              hipStream_t stream) {
  const float* Q  = (const float*)d_in[0];
  const float* K  = (const float*)d_in[1];
  const float* V  = (const float*)d_in[2];
  const float* R  = (const float*)d_in[3];
  const int*   Mk = (const int*)d_in[4];
  float* ans  = (float*)d_out;
  float* pout = ans + (size_t)4 * 8 * 512 * 64;  // p_attn region (SK bf16 staged in-place)
  (void)d_ws; (void)ws_size; (void)in_sizes; (void)n_in; (void)out_size;

  hipLaunchKernelGGL(qk_mfma, dim3(2048), dim3(256), 0, stream, Q, K, pout);
  hipLaunchKernelGGL(attn_v10, dim3(2048), dim3(512), 0, stream,
                     Q, R, Mk, ans, pout);
  hipLaunchKernelGGL(pv_mfma, dim3(512), dim3(512), 0, stream, V, pout, ans);
}

// Round 12
// 103.920 us; speedup vs baseline: 1.1115x; 1.0207x over previous
//
#include <hip/hip_runtime.h>

// Rel-pos attention, r12: K2 staging deepened to QUARTERS (4 x 32 KB) with
// loads-always-in-flight: issue(q+1) -> barrier -> rel(q) -> write(q+1).
// K1 (SK bf16 packed in pout rows) and K3 byte-identical to r11.
// B=4, H=8, S=512, D=64.

typedef __attribute__((ext_vector_type(8))) short short8;
typedef __attribute__((ext_vector_type(4))) float f32x4;

#define MFMA16(a, b, c) __builtin_amdgcn_mfma_f32_16x16x32_bf16(a, b, c, 0, 0, 0)

__device__ __forceinline__ unsigned short f2bf(float x) {
  unsigned int u = __float_as_uint(x);
  u += 0x7fffu + ((u >> 16) & 1u);   // RNE
  return (unsigned short)(u >> 16);
}
__device__ __forceinline__ float bf2f(unsigned int s) {
  return __uint_as_float(s << 16);
}
__device__ __forceinline__ short8 pack8(const float4& a, const float4& b) {
  short8 r;
  r[0] = (short)f2bf(a.x); r[1] = (short)f2bf(a.y);
  r[2] = (short)f2bf(a.z); r[3] = (short)f2bf(a.w);
  r[4] = (short)f2bf(b.x); r[5] = (short)f2bf(b.y);
  r[6] = (short)f2bf(b.z); r[7] = (short)f2bf(b.w);
  return r;
}
__device__ __forceinline__ int RLI(int t, int d) {
  return ((t << 6) | d) ^ ((((t & 7) ^ ((t >> 3) & 7))) << 3);
}
__device__ __forceinline__ int SBI(int h, int t) {
  return ((h << 9) | t) ^ ((h & 7) << 3);
}

// ---------------- K1: SK = Q.K^T per (b,h), bf16 packed into pout rows ----
__global__ __launch_bounds__(256, 4)
void qk_mfma(const float* __restrict__ Q, const float* __restrict__ K,
             float* __restrict__ pout) {
  const int bh   = blockIdx.x >> 6;
  const int tile = blockIdx.x & 63;
  const int s0 = (tile >> 3) << 6;
  const int t0 = (tile & 7) << 6;
  const int w    = threadIdx.x >> 6;
  const int lane = threadIdx.x & 63;
  const int rrow = lane & 15;
  const int kg   = lane >> 4;

  const float* Qb = Q + ((size_t)bh << 15);
  const float* Kb = K + ((size_t)bh << 15);

  const float* qp = Qb + (((s0 + (w << 4) + rrow) << 6) + (kg << 3));
  const short8 a0 = pack8(*reinterpret_cast<const float4*>(qp),
                          *reinterpret_cast<const float4*>(qp + 4));
  const short8 a1 = pack8(*reinterpret_cast<const float4*>(qp + 32),
                          *reinterpret_cast<const float4*>(qp + 36));

  float* pb = pout + ((size_t)bh << 18);

  float4 b0, b1, b2, b3;
  {
    const float* kp = Kb + (((t0 + rrow) << 6) + (kg << 3));
    b0 = *reinterpret_cast<const float4*>(kp);
    b1 = *reinterpret_cast<const float4*>(kp + 4);
    b2 = *reinterpret_cast<const float4*>(kp + 32);
    b3 = *reinterpret_cast<const float4*>(kp + 36);
  }
#pragma unroll
  for (int nt = 0; nt < 4; ++nt) {
    const short8 bb0 = pack8(b0, b1);
    const short8 bb1 = pack8(b2, b3);
    if (nt < 3) {
      const float* kp = Kb + (((t0 + ((nt + 1) << 4) + rrow) << 6) + (kg << 3));
      b0 = *reinterpret_cast<const float4*>(kp);
      b1 = *reinterpret_cast<const float4*>(kp + 4);
      b2 = *reinterpret_cast<const float4*>(kp + 32);
      b3 = *reinterpret_cast<const float4*>(kp + 36);
    }
    f32x4 c = {0.0f, 0.0f, 0.0f, 0.0f};
    c = MFMA16(a0, bb0, c);
    c = MFMA16(a1, bb1, c);
    const int tcol = t0 + (nt << 4) + rrow;
    const int srow = s0 + (w << 4) + (kg << 2);
#pragma unroll
    for (int r = 0; r < 4; ++r) {
      unsigned short* ob =
          reinterpret_cast<unsigned short*>(pb + ((size_t)(srow + r) << 9));
      ob[tcol] = f2bf(c[r]);
    }
  }
}

// ---------------- K2: per (b,s): rel + softmax + ans2, quartered pipe -----
__global__ __launch_bounds__(512, 4)
void attn_v11(const float* __restrict__ Q, const float* __restrict__ R,
              const int* __restrict__ Mk, float* __restrict__ ans,
              float* __restrict__ pout) {
  __shared__ __align__(16) unsigned short smem[8 * 512 + 512 * 64];  // 72 KB
  __shared__ __align__(16) float Pp[4][8][16];                        // 2 KB
  unsigned short* Sb = smem;
  unsigned short* Rl = smem + 8 * 512;

  const int tid = threadIdx.x;
  const int b = blockIdx.x >> 9;
  const int s = blockIdx.x & 511;
  const int bh0 = b << 3;

  const float* Rg = R + ((size_t)((b << 9) + s) << 15);

  const int d4 = tid & 15;     // float4 col
  const int tr = tid >> 4;     // 0..31

  const int lane = tid & 63;
  const int w    = tid >> 6;   // 0..7
  const int nn   = lane & 15;
  const int kg   = lane >> 4;

  // staging helpers: quarter q covers t in [q*128, q*128+128)
  auto LOADQ = [&](int q, float4 (&buf)[4]) {
#pragma unroll
    for (int j = 0; j < 4; ++j)
      buf[j] = *reinterpret_cast<const float4*>(
          Rg + (((q << 7) + (j << 5) + tr) << 6) + (d4 << 2));
  };
  auto WRITEQ = [&](int q, const float4 (&buf)[4]) {
#pragma unroll
    for (int j = 0; j < 4; ++j) {
      const int t = (q << 7) + (j << 5) + tr;
      unsigned short* dst = &Rl[RLI(t, d4 << 2)];
      dst[0] = f2bf(buf[j].x); dst[1] = f2bf(buf[j].y);
      dst[2] = f2bf(buf[j].z); dst[3] = f2bf(buf[j].w);
    }
  };

  float4 bufA[4], bufB[4];
  LOADQ(0, bufA);

  // ---- hoist SK (bf16 in pout row) + mask (consumed at softmax) ----
  float* po = pout + ((size_t)(bh0 + w) << 18) + ((size_t)s << 9);
  const unsigned short* skw = reinterpret_cast<const unsigned short*>(po);
  unsigned int skv[8];
  float biasv[8];
#pragma unroll
  for (int k = 0; k < 8; ++k) {
    skv[k] = skw[lane + (k << 6)];
    biasv[k] = Mk[(b << 9) + lane + (k << 6)] ? 0.0f : -1.0e9f;
  }

  // ---- rel A-frags (Q) ----
  const int hq = nn & 7;
  const float* Qg = Q + ((size_t)(((bh0 + hq) << 9) + s) << 6);
  const short8 aq0 = pack8(*reinterpret_cast<const float4*>(Qg + (kg << 3)),
                           *reinterpret_cast<const float4*>(Qg + (kg << 3) + 4));
  const short8 aq1 = pack8(*reinterpret_cast<const float4*>(Qg + 32 + (kg << 3)),
                           *reinterpret_cast<const float4*>(Qg + 36 + (kg << 3)));

  auto RELQ = [&](int q) {
    const int t0 = (q << 7) + (w << 4);
    const short8 bb0 = *reinterpret_cast<const short8*>(&Rl[RLI(t0 + nn, kg << 3)]);
    const short8 bb1 = *reinterpret_cast<const short8*>(&Rl[RLI(t0 + nn, 32 + (kg << 3))]);
    f32x4 c = {0.0f, 0.0f, 0.0f, 0.0f};
    c = MFMA16(aq0, bb0, c);
    c = MFMA16(aq1, bb1, c);
    if (kg < 2) {
#pragma unroll
      for (int r = 0; r < 4; ++r)
        Sb[SBI((kg << 2) + r, t0 + nn)] = f2bf(c[r]);
    }
  };

  // ---- quartered pipeline: loads for q+1 in flight during rel(q) ----
  WRITEQ(0, bufA);
  LOADQ(1, bufB);
  __syncthreads();
  RELQ(0);
  WRITEQ(1, bufB);
  LOADQ(2, bufA);
  __syncthreads();
  RELQ(1);
  WRITEQ(2, bufA);
  LOADQ(3, bufB);
  __syncthreads();
  RELQ(2);
  WRITEQ(3, bufB);
  __syncthreads();
  RELQ(3);
  __syncthreads();

  // ---- softmax row h = w: (rel + SK)/8 + mask -> p ----
  {
    const int h = w;
    float v[8];
#pragma unroll
    for (int k = 0; k < 8; ++k) {
      const int t = lane + (k << 6);
      v[k] = (bf2f((unsigned int)Sb[SBI(h, t)]) + bf2f(skv[k])) * 0.125f +
             biasv[k];
    }
    float m = v[0];
#pragma unroll
    for (int k = 1; k < 8; ++k) m = fmaxf(m, v[k]);
    m = fmaxf(m, __shfl_xor(m, 1));
    m = fmaxf(m, __shfl_xor(m, 2));
    m = fmaxf(m, __shfl_xor(m, 4));
    m = fmaxf(m, __shfl_xor(m, 8));
    m = fmaxf(m, __shfl_xor(m, 16));
    m = fmaxf(m, __shfl_xor(m, 32));

    float e[8], ss = 0.0f;
#pragma unroll
    for (int k = 0; k < 8; ++k) { e[k] = __expf(v[k] - m); ss += e[k]; }
    ss += __shfl_xor(ss, 1);
    ss += __shfl_xor(ss, 2);
    ss += __shfl_xor(ss, 4);
    ss += __shfl_xor(ss, 8);
    ss += __shfl_xor(ss, 16);
    ss += __shfl_xor(ss, 32);
    const float inv = 1.0f / ss;

#pragma unroll
    for (int k = 0; k < 8; ++k) {
      const float p = e[k] * inv;
      const int t = lane + (k << 6);
      po[t] = p;
      Sb[SBI(h, t)] = f2bf(p);
    }
  }
  __syncthreads();

  // ---- ans2[h,d] = sum_t P[h,t].R[t,d]; 8 waves = (d-tile, k-half) ----
  {
    const int dt = w & 3;
    const int kh = (w >> 2) & 1;
    const int n0 = dt << 4;

    f32x4 acc = {0.0f, 0.0f, 0.0f, 0.0f};
#pragma unroll
    for (int k8 = 0; k8 < 8; ++k8) {
      const int tb = (((kh << 3) + k8) << 5) + (kg << 3);
      const short8 af = *reinterpret_cast<const short8*>(&Sb[SBI(nn, tb)]);
      short8 bf;
#pragma unroll
      for (int j = 0; j < 8; ++j)
        bf[j] = (short)Rl[RLI(tb + j, n0 + nn)];
      acc = MFMA16(af, bf, acc);
    }
    if (kh == 1 && kg < 2) {
#pragma unroll
      for (int r = 0; r < 4; ++r)
        Pp[dt][(kg << 2) + r][nn] = acc[r];
    }
    __syncthreads();
    if (kh == 0 && kg < 2) {
#pragma unroll
      for (int r = 0; r < 4; ++r) {
        const int h = (kg << 2) + r;
        ans[((size_t)(((bh0 + h) << 9) + s) << 6) + n0 + nn] =
            acc[r] + Pp[dt][h][nn];
      }
    }
  }
}

// ---------------- K3: ans += P.V per (b,h,32-row s-tile), 512 threads -----
__global__ __launch_bounds__(512, 4)
void pv_mfma(const float* __restrict__ V, const float* __restrict__ pout,
             float* __restrict__ ans) {
  __shared__ __align__(16) unsigned short Vl[512 * 64];   // 64 KB

  const int tid = threadIdx.x;
  const int bh = blockIdx.x >> 4;
  const int s0 = (blockIdx.x & 15) << 5;

  const float* Vg = V + ((size_t)bh << 15);
  {
    const int d4 = tid & 15;
    const int tr = tid >> 4;     // 0..31
#pragma unroll
    for (int pg = 0; pg < 2; ++pg) {
      float4 tmp[8];
#pragma unroll
      for (int j = 0; j < 8; ++j) {
        const int t = (pg << 8) + (j << 5) + tr;
        tmp[j] = *reinterpret_cast<const float4*>(Vg + (t << 6) + (d4 << 2));
      }
#pragma unroll
      for (int j = 0; j < 8; ++j) {
        const int t = (pg << 8) + (j << 5) + tr;
        unsigned short* dst = &Vl[RLI(t, d4 << 2)];
        dst[0] = f2bf(tmp[j].x); dst[1] = f2bf(tmp[j].y);
        dst[2] = f2bf(tmp[j].z); dst[3] = f2bf(tmp[j].w);
      }
    }
  }
  __syncthreads();

  const int lane = tid & 63;
  const int w    = tid >> 6;     // 0..7
  const int nn   = lane & 15;
  const int kg   = lane >> 4;
  const int rw   = w & 1;
  const int cq   = w >> 1;
  const int n0   = cq << 4;
  const int srow = s0 + (rw << 4) + nn;

  const float* Pg = pout + ((size_t)bh << 18) + ((size_t)srow << 9);

  f32x4 acc = {0.f, 0.f, 0.f, 0.f};

  float4 pa = *reinterpret_cast<const float4*>(Pg + (kg << 3));
  float4 pb = *reinterpret_cast<const float4*>(Pg + (kg << 3) + 4);
#pragma unroll
  for (int ks = 0; ks < 16; ++ks) {
    const short8 af = pack8(pa, pb);
    if (ks < 15) {
      pa = *reinterpret_cast<const float4*>(Pg + ((ks + 1) << 5) + (kg << 3));
      pb = *reinterpret_cast<const float4*>(Pg + ((ks + 1) << 5) + (kg << 3) + 4);
    }
    const int tb = (ks << 5) + (kg << 3);
    short8 bf;
#pragma unroll
    for (int j = 0; j < 8; ++j)
      bf[j] = (short)Vl[RLI(tb + j, n0 + nn)];
    acc = MFMA16(af, bf, acc);
  }

  {
    const int sb = s0 + (rw << 4) + (kg << 2);
#pragma unroll
    for (int r = 0; r < 4; ++r) {
      float* ap = ans + ((size_t)bh << 15) + ((size_t)(sb + r) << 6) + n0 + nn;
      ap[0] += acc[r];
    }
  }
}

extern "C" void kernel_launch(void* const* d_in, const int* in_sizes, int n_in,
                              void* d_out, int out_size, void* d_ws, size_t ws_size,
                              hipStream_t stream) {
  const float* Q  = (const float*)d_in[0];
  const float* K  = (const float*)d_in[1];
  const float* V  = (const float*)d_in[2];
  const float* R  = (const float*)d_in[3];
  const int*   Mk = (const int*)d_in[4];
  float* ans  = (float*)d_out;
  float* pout = ans + (size_t)4 * 8 * 512 * 64;  // p_attn region (SK bf16 staged in-place)
  (void)d_ws; (void)ws_size; (void)in_sizes; (void)n_in; (void)out_size;

  hipLaunchKernelGGL(qk_mfma, dim3(2048), dim3(256), 0, stream, Q, K, pout);
  hipLaunchKernelGGL(attn_v11, dim3(2048), dim3(512), 0, stream,
                     Q, R, Mk, ans, pout);
  hipLaunchKernelGGL(pv_mfma, dim3(512), dim3(512), 0, stream, V, pout, ans);
}